// Round 17
// baseline (303.881 us; speedup 1.0000x reference)
//
#include <hip/hip_runtime.h>

#define N_NODES 102
#define NP 8192          // pairs (B*n)
#define RBLOCKS 3264     // 256-row blocks
#define RSTRIDE 128      // persistent grid x-dim

typedef _Float16 f16x8 __attribute__((ext_vector_type(8)));
typedef _Float16 f16x2 __attribute__((ext_vector_type(2)));
typedef float f32x4 __attribute__((ext_vector_type(4)));

// ---------------- Kernel 1: build sparse propagation tables ----------------------
__global__ void build_tables(const int* __restrict__ ei, int ne,
                             int4* __restrict__ gtu, float4* __restrict__ gtw) {
    __shared__ int   deg[N_NODES];
    __shared__ float dinv[N_NODES];
    __shared__ int   cnt[N_NODES];
    __shared__ int   tu[N_NODES][4];
    __shared__ float tw[N_NODES][4];
    int t = threadIdx.x;
    if (t < N_NODES) deg[t] = 1;                       // self-loop
    __syncthreads();
    if (t == 0) for (int e = 0; e < ne; ++e) deg[ei[ne + e]] += 1;
    __syncthreads();
    if (t < N_NODES) {
        dinv[t] = 1.0f / sqrtf((float)deg[t]);
        cnt[t] = 1;
        for (int j = 0; j < 4; ++j) { tu[t][j] = 2 * t; tw[t][j] = 0.0f; }
    }
    __syncthreads();
    if (t < N_NODES) tw[t][0] = dinv[t] * dinv[t];     // diagonal self-loop
    __syncthreads();
    if (t == 0) {
        for (int e = 0; e < ne; ++e) {
            int r = ei[e], c = ei[ne + e];
            int s = cnt[c] < 4 ? cnt[c] : 3;           // clamp (never hit here)
            cnt[c] = s + 1;
            tu[c][s] = 2 * r;
            tw[c][s] = dinv[r] * dinv[c];
        }
    }
    __syncthreads();
    if (t < N_NODES) {
        gtu[t] = make_int4(tu[t][0], tu[t][1], tu[t][2], tu[t][3]);
        gtw[t] = make_float4(tw[t][0], tw[t][1], tw[t][2], tw[t][3]);
    }
}

// ---------------- Kernel 1b: WpT[col][k] = (f16)Wp[k][col] (proven in R13) -------
__global__ void prep_w(const float* __restrict__ Wp, _Float16* __restrict__ WpT) {
    int tid = blockIdx.x * 256 + threadIdx.x;          // 64 x 256 = 16384
    for (int i = tid; i < 65536; i += 16384) {         // i = k*256 + col (coalesced)
        int col = i & 255, k = i >> 8;
        WpT[col * 256 + k] = (_Float16)Wp[i];
    }
}

// ---------------- Kernel 2: persistent fused GNN, barrier-free loop --------------
// R15-verbatim EXCEPT: xs staging is PER-WAVE (each wave stages the <=2 x-pairs
// its 64 rows span into its own LDS quadrant) -> NO __syncthreads in the loop.
// Waves free-run; iter-j stores pipeline under iter-j+1 compute (removes the
// per-iteration s_waitcnt vmcnt(0) barrier drain that serialized R15).
__global__ __launch_bounds__(256, 2) void gnn_main(
    const float* __restrict__ x,       // [NP][204] fp32
    const _Float16* __restrict__ WpT,  // [256 col][256 k] f16
    const int4*  __restrict__ gtu,     // [102]
    const float4* __restrict__ gtw,    // [102]
    const float* __restrict__ Wg,      // [2][256]
    const float* __restrict__ bg,      // [256]
    const float* __restrict__ bp,      // [256]
    float* __restrict__ out)           // [R][256]
{
    __shared__ float xs[4][2 * 2 * N_NODES];   // per-wave: 2 pairs = 408 floats
    __shared__ int4   stu[N_NODES];
    __shared__ float4 stw[N_NODES];
    __shared__ _Float16 W0l[256], W1l[256], bgl[256];
    const int tid = threadIdx.x;
    const int w  = tid >> 6;
    const int l  = tid & 63;
    const int qk = l >> 4;
    const int m  = l & 15;
    const int c0  = blockIdx.y * 64;
    const int rbi = blockIdx.x;

    // Hoist all B fragments into registers (32 x 16B, L2-resident WpT)
    f16x8 bfragR[8][4];
    #pragma unroll
    for (int t = 0; t < 8; ++t)
        #pragma unroll
        for (int nt = 0; nt < 4; ++nt)
            bfragR[t][nt] = *reinterpret_cast<const f16x8*>(
                &WpT[(c0 + nt * 16 + m) * 256 + qk * 8 + 32 * t]);

    // Stage tables + GNN weights (once; single barrier before loop)
    if (tid < N_NODES) { stu[tid] = gtu[tid]; stw[tid] = gtw[tid]; }
    W0l[tid] = (_Float16)Wg[tid];
    W1l[tid] = (_Float16)Wg[256 + tid];
    bgl[tid] = (_Float16)bg[tid];

    float bpf[4];
    #pragma unroll
    for (int nt = 0; nt < 4; ++nt) bpf[nt] = bp[c0 + nt * 16 + m];

    __syncthreads();

    const f16x2 z2 = (f16x2){ (_Float16)0.0f, (_Float16)0.0f };
    float* xsw = xs[w];

    #pragma unroll 1
    for (int j = 0; j < 26; ++j) {
        const int rb = rbi + j * RSTRIDE;
        if (rb >= RBLOCKS) break;
        const int rowblk = rb * 256;
        const int wrow0  = rowblk + w * 64;
        const int p0     = wrow0 / N_NODES;

        // Per-wave staging of 2 x-pairs (408 floats, coalesced; no barrier)
        {
            const size_t gbase = (size_t)p0 * (2 * N_NODES);
            const size_t gmax  = (size_t)NP * (2 * N_NODES);
            #pragma unroll
            for (int i = 0; i < 7; ++i) {
                int idx = l + i * 64;
                if (idx < 2 * 2 * N_NODES)
                    xsw[idx] = (gbase + idx < gmax) ? x[gbase + idx] : 0.0f;
            }
        }
        // (wave-internal lgkmcnt ordering; no __syncthreads needed)

        // y-gen from sparse tables
        f16x2 y0pk[4], y1pk[4];
        #pragma unroll
        for (int s = 0; s < 4; ++s) {
            int r = wrow0 + s * 16 + m;
            int p = r / N_NODES;
            int v = r - p * N_NODES;
            const float* xp = &xsw[(p - p0) * 2 * N_NODES];
            int4  U = stu[v];
            float4 W = stw[v];
            float a0 = W.x * xp[U.x]     + W.y * xp[U.y]
                     + W.z * xp[U.z]     + W.w * xp[U.w];
            float a1 = W.x * xp[U.x + 1] + W.y * xp[U.y + 1]
                     + W.z * xp[U.z + 1] + W.w * xp[U.w + 1];
            _Float16 h0 = (_Float16)a0;
            _Float16 h1 = (_Float16)a1;
            y0pk[s] = (f16x2){ h0, h0 };
            y1pk[s] = (f16x2){ h1, h1 };
        }

        f32x4 acc[4][4];
        #pragma unroll
        for (int s = 0; s < 4; ++s)
            #pragma unroll
            for (int nt = 0; nt < 4; ++nt)
                acc[s][nt] = (f32x4){0.f, 0.f, 0.f, 0.f};

        #pragma unroll
        for (int t = 0; t < 8; ++t) {
            const int kk = qk * 8 + 32 * t;
            union { f16x8 v; f16x2 p[4]; } w0u, w1u, bbu;
            w0u.v = *reinterpret_cast<const f16x8*>(&W0l[kk]);
            w1u.v = *reinterpret_cast<const f16x8*>(&W1l[kk]);
            bbu.v = *reinterpret_cast<const f16x8*>(&bgl[kk]);
            #pragma unroll
            for (int s = 0; s < 4; ++s) {
                union { f16x8 v; f16x2 p[4]; } af;
                #pragma unroll
                for (int j2 = 0; j2 < 4; ++j2) {
                    f16x2 h = w0u.p[j2] * y0pk[s] + w1u.p[j2] * y1pk[s] + bbu.p[j2];
                    af.p[j2] = __builtin_elementwise_max(h, z2);
                }
                #pragma unroll
                for (int nt = 0; nt < 4; ++nt)
                    acc[s][nt] = __builtin_amdgcn_mfma_f32_16x16x32_f16(af.v, bfragR[t][nt], acc[s][nt], 0, 0, 0);
            }
        }

        // Epilogue: + b_proj, scalar stores (R9-verbatim)
        const long rowbase = (long)wrow0;
        #pragma unroll
        for (int s = 0; s < 4; ++s) {
            #pragma unroll
            for (int nt = 0; nt < 4; ++nt) {
                const int e = c0 + nt * 16 + m;
                #pragma unroll
                for (int reg = 0; reg < 4; ++reg) {
                    long r = rowbase + s * 16 + qk * 4 + reg;
                    out[r * 256 + e] = acc[s][nt][reg] + bpf[nt];
                }
            }
        }
    }
}

extern "C" void kernel_launch(void* const* d_in, const int* in_sizes, int n_in,
                              void* d_out, int out_size, void* d_ws, size_t ws_size,
                              hipStream_t stream) {
    const float* x  = (const float*)d_in[0];
    const float* Wg = (const float*)d_in[1];
    const float* bg = (const float*)d_in[2];
    const float* Wp = (const float*)d_in[3];
    const float* bp = (const float*)d_in[4];
    const int* ei   = (const int*)d_in[5];
    float* out = (float*)d_out;

    const int ne = in_sizes[5] / 2;                 // 84

    int4*     gtu = (int4*)d_ws;                        // 102 int4
    float4*   gtw = (float4*)((char*)d_ws + 2048);      // 102 float4
    _Float16* WpT = (_Float16*)((char*)d_ws + 4096);    // 65536 f16 = 128 KB

    build_tables<<<1, 128, 0, stream>>>(ei, ne, gtu, gtw);
    prep_w<<<64, 256, 0, stream>>>(Wp, WpT);

    gnn_main<<<dim3(RSTRIDE, 4), 256, 0, stream>>>(x, WpT, gtu, gtw, Wg, bg, bp, out);
}

// Round 18
// 214.223 us; speedup vs baseline: 1.4185x; 1.4185x over previous
//
#include <hip/hip_runtime.h>

#define N_NODES 102
#define NP 8192          // pairs (B*n)
#define RBLOCKS 3264     // 256-row blocks
#define RSTRIDE 128      // persistent grid x-dim

typedef _Float16 f16x8 __attribute__((ext_vector_type(8)));
typedef _Float16 f16x2 __attribute__((ext_vector_type(2)));
typedef float f32x4 __attribute__((ext_vector_type(4)));

// ---------------- Kernel 1: build sparse propagation tables ----------------------
__global__ void build_tables(const int* __restrict__ ei, int ne,
                             int4* __restrict__ gtu, float4* __restrict__ gtw) {
    __shared__ int   deg[N_NODES];
    __shared__ float dinv[N_NODES];
    __shared__ int   cnt[N_NODES];
    __shared__ int   tu[N_NODES][4];
    __shared__ float tw[N_NODES][4];
    int t = threadIdx.x;
    if (t < N_NODES) deg[t] = 1;                       // self-loop
    __syncthreads();
    if (t == 0) for (int e = 0; e < ne; ++e) deg[ei[ne + e]] += 1;
    __syncthreads();
    if (t < N_NODES) {
        dinv[t] = 1.0f / sqrtf((float)deg[t]);
        cnt[t] = 1;
        for (int j = 0; j < 4; ++j) { tu[t][j] = 2 * t; tw[t][j] = 0.0f; }
    }
    __syncthreads();
    if (t < N_NODES) tw[t][0] = dinv[t] * dinv[t];     // diagonal self-loop
    __syncthreads();
    if (t == 0) {
        for (int e = 0; e < ne; ++e) {
            int r = ei[e], c = ei[ne + e];
            int s = cnt[c] < 4 ? cnt[c] : 3;           // clamp (never hit here)
            cnt[c] = s + 1;
            tu[c][s] = 2 * r;
            tw[c][s] = dinv[r] * dinv[c];
        }
    }
    __syncthreads();
    if (t < N_NODES) {
        gtu[t] = make_int4(tu[t][0], tu[t][1], tu[t][2], tu[t][3]);
        gtw[t] = make_float4(tw[t][0], tw[t][1], tw[t][2], tw[t][3]);
    }
}

// ---------------- Kernel 1b: WpT[col][k] = (f16)Wp[k][col] (proven in R13) -------
__global__ void prep_w(const float* __restrict__ Wp, _Float16* __restrict__ WpT) {
    int tid = blockIdx.x * 256 + threadIdx.x;          // 64 x 256 = 16384
    for (int i = tid; i < 65536; i += 16384) {         // i = k*256 + col (coalesced)
        int col = i & 255, k = i >> 8;
        WpT[col * 256 + k] = (_Float16)Wp[i];
    }
}

// ---------------- Kernel 2: persistent fused GNN, async-staged x -----------------
// R15-verbatim EXCEPT (T14 split): next iteration's x staged to REGISTERS early
// in the compute phase (older than the epilogue stores in the in-order vmcnt
// queue), written to LDS from regs next iter; raw s_barrier + lgkmcnt(0) only
// (no __syncthreads vmcnt(0) drain). Compute phase has ZERO global loads ->
// iter-j stores ack under iter-j+1 compute.
__global__ __launch_bounds__(256, 2) void gnn_main(
    const float* __restrict__ x,       // [NP][204] fp32
    const _Float16* __restrict__ WpT,  // [256 col][256 k] f16
    const int4*  __restrict__ gtu,     // [102]
    const float4* __restrict__ gtw,    // [102]
    const float* __restrict__ Wg,      // [2][256]
    const float* __restrict__ bg,      // [256]
    const float* __restrict__ bp,      // [256]
    float* __restrict__ out)           // [R][256]
{
    __shared__ float xs[4 * 2 * N_NODES];   // 3.3 KB
    __shared__ int4   stu[N_NODES];
    __shared__ float4 stw[N_NODES];
    __shared__ _Float16 W0l[256], W1l[256], bgl[256];
    const int tid = threadIdx.x;
    const int w  = tid >> 6;
    const int l  = tid & 63;
    const int qk = l >> 4;
    const int m  = l & 15;
    const int c0  = blockIdx.y * 64;
    const int rbi = blockIdx.x;

    // Hoist all B fragments into registers (32 x 16B, L2-resident WpT)
    f16x8 bfragR[8][4];
    #pragma unroll
    for (int t = 0; t < 8; ++t)
        #pragma unroll
        for (int nt = 0; nt < 4; ++nt)
            bfragR[t][nt] = *reinterpret_cast<const f16x8*>(
                &WpT[(c0 + nt * 16 + m) * 256 + qk * 8 + 32 * t]);

    // Stage tables + GNN weights (once)
    if (tid < N_NODES) { stu[tid] = gtu[tid]; stw[tid] = gtw[tid]; }
    W0l[tid] = (_Float16)Wg[tid];
    W1l[tid] = (_Float16)Wg[256 + tid];
    bgl[tid] = (_Float16)bg[tid];

    float bpf[4];
    #pragma unroll
    for (int nt = 0; nt < 4; ++nt) bpf[nt] = bp[c0 + nt * 16 + m];

    // Prologue prefetch: x slice for iteration 0 into registers
    float px[4];
    {
        const int pb0 = (rbi * 256) / N_NODES;
        #pragma unroll
        for (int pi = 0; pi < 4; ++pi) {
            int p = pb0 + pi;
            px[pi] = (tid < 2 * N_NODES && p < NP) ? x[(size_t)p * (2 * N_NODES) + tid] : 0.0f;
        }
    }
    __syncthreads();   // weights/tables staged; px loads drained (once)

    const f16x2 z2 = (f16x2){ (_Float16)0.0f, (_Float16)0.0f };

    #pragma unroll 1
    for (int j = 0; j < 26; ++j) {
        const int rb = rbi + j * RSTRIDE;
        if (rb >= RBLOCKS) break;
        const int rowblk = rb * 256;
        const int pbase  = rowblk / N_NODES;

        // Barrier #1: all waves done READING xs from previous iteration
        __builtin_amdgcn_s_barrier();

        // Write this iteration's xs from registers (lgkmcnt only)
        if (tid < 2 * N_NODES) {
            #pragma unroll
            for (int pi = 0; pi < 4; ++pi)
                xs[pi * 2 * N_NODES + tid] = px[pi];
        }

        // Issue NEXT iteration's x prefetch now (older than this iter's stores)
        float pxn[4];
        {
            const int rbn = rbi + (j + 1) * RSTRIDE;
            const bool ok = (rbn < RBLOCKS);
            const int pbn = ok ? (rbn * 256) / N_NODES : 0;
            #pragma unroll
            for (int pi = 0; pi < 4; ++pi) {
                int p = pbn + pi;
                pxn[pi] = (ok && tid < 2 * N_NODES && p < NP)
                              ? x[(size_t)p * (2 * N_NODES) + tid] : 0.0f;
            }
        }

        // Barrier #2: xs visible to all waves (lgkm drain only — NO vmcnt drain)
        asm volatile("s_waitcnt lgkmcnt(0)" ::: "memory");
        __builtin_amdgcn_sched_barrier(0);
        __builtin_amdgcn_s_barrier();
        __builtin_amdgcn_sched_barrier(0);

        // y-gen from sparse tables (R15-verbatim)
        f16x2 y0pk[4], y1pk[4];
        #pragma unroll
        for (int s = 0; s < 4; ++s) {
            int r = rowblk + w * 64 + s * 16 + m;
            int p = r / N_NODES;
            int v = r - p * N_NODES;
            const float* xp = &xs[(p - pbase) * 2 * N_NODES];
            int4  U = stu[v];
            float4 W = stw[v];
            float a0 = W.x * xp[U.x]     + W.y * xp[U.y]
                     + W.z * xp[U.z]     + W.w * xp[U.w];
            float a1 = W.x * xp[U.x + 1] + W.y * xp[U.y + 1]
                     + W.z * xp[U.z + 1] + W.w * xp[U.w + 1];
            _Float16 h0 = (_Float16)a0;
            _Float16 h1 = (_Float16)a1;
            y0pk[s] = (f16x2){ h0, h0 };
            y1pk[s] = (f16x2){ h1, h1 };
        }

        f32x4 acc[4][4];
        #pragma unroll
        for (int s = 0; s < 4; ++s)
            #pragma unroll
            for (int nt = 0; nt < 4; ++nt)
                acc[s][nt] = (f32x4){0.f, 0.f, 0.f, 0.f};

        #pragma unroll
        for (int t = 0; t < 8; ++t) {
            const int kk = qk * 8 + 32 * t;
            union { f16x8 v; f16x2 p[4]; } w0u, w1u, bbu;
            w0u.v = *reinterpret_cast<const f16x8*>(&W0l[kk]);
            w1u.v = *reinterpret_cast<const f16x8*>(&W1l[kk]);
            bbu.v = *reinterpret_cast<const f16x8*>(&bgl[kk]);
            #pragma unroll
            for (int s = 0; s < 4; ++s) {
                union { f16x8 v; f16x2 p[4]; } af;
                #pragma unroll
                for (int j2 = 0; j2 < 4; ++j2) {
                    f16x2 h = w0u.p[j2] * y0pk[s] + w1u.p[j2] * y1pk[s] + bbu.p[j2];
                    af.p[j2] = __builtin_elementwise_max(h, z2);
                }
                #pragma unroll
                for (int nt = 0; nt < 4; ++nt)
                    acc[s][nt] = __builtin_amdgcn_mfma_f32_16x16x32_f16(af.v, bfragR[t][nt], acc[s][nt], 0, 0, 0);
            }
        }

        // Epilogue: + b_proj, scalar stores (R15-verbatim)
        const long rowbase = (long)rowblk + (long)w * 64;
        #pragma unroll
        for (int s = 0; s < 4; ++s) {
            #pragma unroll
            for (int nt = 0; nt < 4; ++nt) {
                const int e = c0 + nt * 16 + m;
                #pragma unroll
                for (int reg = 0; reg < 4; ++reg) {
                    long r = rowbase + s * 16 + qk * 4 + reg;
                    out[r * 256 + e] = acc[s][nt][reg] + bpf[nt];
                }
            }
        }

        #pragma unroll
        for (int pi = 0; pi < 4; ++pi) px[pi] = pxn[pi];
    }
}

extern "C" void kernel_launch(void* const* d_in, const int* in_sizes, int n_in,
                              void* d_out, int out_size, void* d_ws, size_t ws_size,
                              hipStream_t stream) {
    const float* x  = (const float*)d_in[0];
    const float* Wg = (const float*)d_in[1];
    const float* bg = (const float*)d_in[2];
    const float* Wp = (const float*)d_in[3];
    const float* bp = (const float*)d_in[4];
    const int* ei   = (const int*)d_in[5];
    float* out = (float*)d_out;

    const int ne = in_sizes[5] / 2;                 // 84

    int4*     gtu = (int4*)d_ws;                        // 102 int4
    float4*   gtw = (float4*)((char*)d_ws + 2048);      // 102 float4
    _Float16* WpT = (_Float16*)((char*)d_ws + 4096);    // 65536 f16 = 128 KB

    build_tables<<<1, 128, 0, stream>>>(ei, ne, gtu, gtw);
    prep_w<<<64, 256, 0, stream>>>(Wp, WpT);

    gnn_main<<<dim3(RSTRIDE, 4), 256, 0, stream>>>(x, WpT, gtu, gtw, Wg, bg, bp, out);
}